// Round 18
// baseline (122.000 us; speedup 1.0000x reference)
//
#include <hip/hip_runtime.h>
#include <hip/hip_bf16.h>
#include <stdint.h>

typedef unsigned long long u64;
typedef unsigned int u32;
typedef unsigned short u16;

#define NANCH 10647
#define NBATCH 16
#define NSORT 16384
#define NSEL 2048
#define NWORD 32
#define NCLS 80
#define CONF_T 0.5f
#define NMS_T 0.5f
#define MAXDET 300
#define MAXWH 4096.0f
#define CANDCAP 10688   // >= NANCH, 64-aligned
#define PART 1344       // ceil(NANCH/8) rounded to 64
#define NBLK1 84        // (NANCH+127)/128

// exact inverse of the key's score mapping (bijective bit ops; r16-verified)
__device__ __forceinline__ float dec_score(u64 key) {
    u32 v = ~(u32)(key >> 32);
    u32 u = (v & 0x80000000u) ? (v & 0x7FFFFFFFu) : ~v;
    return __uint_as_float(u);
}

// ---------------- Kernel 1: per-anchor prep (+ per-block top-byte hist) ----------------
__global__ __launch_bounds__(256) void k_prep(const float* __restrict__ pred,
                                              u64* __restrict__ keys,
                                              float4* __restrict__ boxes,
                                              int* __restrict__ cls,
                                              u32* __restrict__ bhist) {
    __shared__ float sm[128 * 85];
    __shared__ u32 ph[256];
    int b = blockIdx.y;
    int a0 = blockIdx.x * 128;
    int na = NANCH - a0; if (na > 128) na = 128;
    const float* src = pred + ((size_t)b * NANCH + a0) * 85;
    int tot = na * 85;
    ph[threadIdx.x] = 0;
    // 16B-aligned float4 staging (align-down + shift; r17-verified)
    {
        size_t srcaddr = (size_t)src;
        int shift = (int)((srcaddr & 15) >> 2);
        const float4* A = (const float4*)(srcaddr & ~(size_t)15);
        int nvec = (tot + shift + 3) >> 2;
        for (int j = threadIdx.x; j < nvec; j += 256) {
            float4 v = A[j];
            int base = 4 * j - shift;
            if (base >= 0 && base + 3 < tot) {
                sm[base] = v.x; sm[base + 1] = v.y;
                sm[base + 2] = v.z; sm[base + 3] = v.w;
            } else {
                if (base >= 0 && base < tot)         sm[base]     = v.x;
                if (base + 1 >= 0 && base + 1 < tot) sm[base + 1] = v.y;
                if (base + 2 >= 0 && base + 2 < tot) sm[base + 2] = v.z;
                if (base + 3 >= 0 && base + 3 < tot) sm[base + 3] = v.w;
            }
        }
    }
    __syncthreads();
    int t = threadIdx.x;
    u64 kk = 0;
    if (t < na) {
        const float* s = &sm[t * 85];
        float x = s[0], y = s[1], w = s[2], h = s[3], obj = s[4];
        float best = s[5] * obj; int arg = 0;
        #pragma unroll
        for (int c = 1; c < 80; ++c) {
            float v = s[5 + c] * obj;
            if (v > best) { best = v; arg = c; }
        }
        bool valid = obj >= CONF_T;
        float sc = valid ? best : -1.0f;
        int a = a0 + t;
        float4 bx;
        bx.x = x - w * 0.5f; bx.y = y - h * 0.5f;
        bx.z = x + w * 0.5f; bx.w = y + h * 0.5f;
        size_t o = (size_t)b * NANCH + a;
        boxes[o] = bx;
        cls[o] = arg;
        u32 u = __float_as_uint(sc);
        u32 v = (u & 0x80000000u) ? ~u : (u | 0x80000000u); // ascending map
        u32 hi = ~v;                                        // descending
        kk = ((u64)hi << 32) | (u32)a;
        keys[(size_t)b * NSORT + a] = kk;
    }
    // wave-aggregated 256-bin histogram of key top byte (block-local)
    u32 bin = (t < na) ? (u32)(kk >> 56) : 0xFFFFFFFFu;
    int lane = t & 63;
    u64 rem = __ballot(t < na);
    while (rem) {
        int srcl = __ffsll((long long)rem) - 1;
        u32 lb = __shfl(bin, srcl);
        u64 same = __ballot(bin == lb) & rem;
        if (lane == srcl) atomicAdd(&ph[lb], (u32)__popcll(same));
        rem &= ~same;
    }
    __syncthreads();
    // unconditional store: no global atomics, no pre-zeroing needed
    bhist[(((size_t)b * NBLK1) + blockIdx.x) * 256 + threadIdx.x] = ph[threadIdx.x];
}

// ---- Kernel 2: deterministic classify scan -> partition slices (no atomics) ----
__global__ __launch_bounds__(1024) void k_scan(const u64* __restrict__ keys,
                                               const u32* __restrict__ bhist,
                                               u64* __restrict__ gslice,
                                               uint2* __restrict__ gpart) {
    __shared__ u32 hist[256];
    __shared__ u32 hsc[256];
    __shared__ u32 s_D0;
    __shared__ u32 wcs[16], wcc[16];
    __shared__ u32 s_tc;
    int b = blockIdx.y;
    int part = blockIdx.x;
    int tid = threadIdx.x;
    int lane = tid & 63, wv = tid >> 6;
    u64 below = (1ULL << lane) - 1ULL;
    const u64* KB = keys + (size_t)b * NSORT;

    // sum the 84 per-block histograms (coalesced across tid)
    if (tid < 256) {
        u32 h = 0;
        const u32* BH = bhist + (size_t)b * NBLK1 * 256 + tid;
        for (int j = 0; j < NBLK1; ++j) h += BH[(size_t)j * 256];
        hist[tid] = h;
    }
    __syncthreads();
    if (tid < 64) {
        u32 h0 = hist[tid*4], h1 = hist[tid*4+1], h2 = hist[tid*4+2], h3 = hist[tid*4+3];
        u32 loc = h0 + h1 + h2 + h3;
        u32 p = loc;
        #pragma unroll
        for (int o = 1; o < 64; o <<= 1) { u32 t2 = __shfl_up(p, o); if (lane >= o) p += t2; }
        u32 base = p - loc;
        hsc[tid*4]   = base + h0;
        hsc[tid*4+1] = base + h0 + h1;
        hsc[tid*4+2] = base + h0 + h1 + h2;
        hsc[tid*4+3] = base + h0 + h1 + h2 + h3;
    }
    __syncthreads();
    if (tid < 256) {
        u32 inc = hsc[tid], cb = inc - hist[tid];
        if (cb < NSEL && NSEL <= inc) s_D0 = tid;
    }
    __syncthreads();
    u32 D0 = s_D0;

    u64 kk0 = 0, kk1 = 0;
    bool s0 = false, s1 = false, c0 = false, c1 = false;
    {
        int off = tid, i = part * PART + off;
        bool inb = (off < PART) && (i < NANCH);
        kk0 = inb ? KB[i] : 0ULL;
        u32 top = (u32)(kk0 >> 56);
        s0 = inb && (top < D0); c0 = inb && (top == D0);
    }
    {
        int off = 1024 + tid, i = part * PART + off;
        bool inb = (off < PART) && (i < NANCH);
        kk1 = inb ? KB[i] : 0ULL;
        u32 top = (u32)(kk1 >> 56);
        s1 = inb && (top < D0); c1 = inb && (top == D0);
    }
    u64 bs0 = __ballot(s0), bs1 = __ballot(s1);
    u64 bc0 = __ballot(c0), bc1 = __ballot(c1);
    if (lane == 0) {
        wcs[wv] = (u32)(__popcll(bs0) + __popcll(bs1));
        wcc[wv] = (u32)(__popcll(bc0) + __popcll(bc1));
    }
    __syncthreads();
    if (tid < 16) {
        u32 vs = wcs[tid], vc = wcc[tid];
        u32 ps = vs, pc = vc;
        #pragma unroll
        for (int o = 1; o < 16; o <<= 1) {
            u32 ts = __shfl_up(ps, o);
            u32 tc = __shfl_up(pc, o);
            if (tid >= o) { ps += ts; pc += tc; }
        }
        wcs[tid] = ps - vs;   // exclusive wave base
        wcc[tid] = pc - vc;
        if (tid == 15) {
            s_tc = pc;
            gpart[(size_t)b * 8 + part] = make_uint2(ps, pc);  // totals
        }
    }
    __syncthreads();
    // sure keys at slice front, boundary keys at slice back (disjoint: ts+tc<=PART)
    u64* SL = gslice + ((size_t)b * 8 + part) * (size_t)PART;
    u32 base_s = wcs[wv];
    u32 base_c = (u32)PART - s_tc + wcc[wv];
    if (s0) SL[base_s + __popcll(bs0 & below)] = kk0;
    if (s1) SL[base_s + __popcll(bs0) + __popcll(bs1 & below)] = kk1;
    if (c0) SL[base_c + __popcll(bc0 & below)] = kk0;
    if (c1) SL[base_c + __popcll(bc0) + __popcll(bc1 & below)] = kk1;
}

// ---- Kernel 3: compact slices + refine threshold + hybrid bitonic -> gskey ----
// Invariant: s_cnt + s_rank == NSEL at every refine-loop entry.
__global__ __launch_bounds__(1024) void k_fin(const u64* __restrict__ gslice,
                                              const uint2* __restrict__ gpart,
                                              u64* __restrict__ gskey,
                                              u64* __restrict__ gkeep) {
    __shared__ u64 sk[NSEL];        // 16 KB
    __shared__ u64 cand[CANDCAP];   // 85.5 KB
    __shared__ u32 hist[256];
    __shared__ u32 hsc[256];
    __shared__ u64 s_red[16];
    __shared__ u32 ssA[8], ccA[8], soff[9], coff[9];
    __shared__ u32 s_D, s_rank, s_cnt, s_cand;

    int b = blockIdx.x;
    int tid = threadIdx.x;
    int lane = tid & 63;
    u64 below = (1ULL << lane) - 1ULL;

    if (tid < 8) { uint2 v = gpart[(size_t)b * 8 + tid]; ssA[tid] = v.x; ccA[tid] = v.y; }
    for (int i = tid; i < NSEL; i += 1024) sk[i] = ~0ULL;   // safety fill
    __syncthreads();
    if (tid == 0) {
        u32 a = 0, c2 = 0;
        for (int j = 0; j < 8; ++j) { soff[j] = a; a += ssA[j]; coff[j] = c2; c2 += ccA[j]; }
        soff[8] = a; coff[8] = c2;
        s_cnt = a; s_rank = NSEL - a; s_cand = c2;
    }
    __syncthreads();
    for (int j = 0; j < 8; ++j) {
        const u64* SL = gslice + ((size_t)b * 8 + j) * (size_t)PART;
        u32 ns = ssA[j], nc = ccA[j];
        u32 so = soff[j], co = coff[j];
        for (u32 i = tid; i < ns; i += 1024) sk[so + i] = SL[i];
        for (u32 i = tid; i < nc; i += 1024) cand[co + i] = SL[PART - nc + i];
    }
    __syncthreads();

    // ---- refine within cand; append sure-members to sk each round ----
    const int shifts2[5] = {48, 40, 32, 8, 0};
    for (int rr = 0; ; ++rr) {
        u32 cn = s_cand, r = s_rank;
        if (r == cn || rr == 5) {
            for (u32 i0 = 0; i0 < cn; i0 += 1024) {
                u32 i = i0 + tid;
                bool take = i < cn;
                u64 kk = take ? cand[i] : 0ULL;
                u64 bt = __ballot(take);
                u32 base = 0;
                if (lane == 0 && bt) base = atomicAdd(&s_cnt, (u32)__popcll(bt));
                base = __shfl(base, 0);
                if (take) sk[base + __popcll(bt & below)] = kk;
            }
            break;
        }
        if (r == 1) {
            u64 best = ~0ULL;
            for (u32 i = tid; i < cn; i += 1024) { u64 kk = cand[i]; if (kk < best) best = kk; }
            #pragma unroll
            for (int o = 32; o > 0; o >>= 1) {
                u64 other = __shfl_down(best, o);
                if (other < best) best = other;
            }
            if (lane == 0) s_red[tid >> 6] = best;
            __syncthreads();
            if (tid == 0) {
                u64 m = s_red[0];
                for (int w2 = 1; w2 < 16; ++w2) if (s_red[w2] < m) m = s_red[w2];
                sk[atomicAdd(&s_cnt, 1u)] = m;
            }
            break;
        }
        int shift = shifts2[rr];
        if (tid < 256) hist[tid] = 0;
        __syncthreads();
        for (u32 i = tid; i < cn; i += 1024)
            atomicAdd(&hist[(u32)(cand[i] >> shift) & 0xFFu], 1u);
        __syncthreads();
        if (tid < 64) {
            u32 h0 = hist[tid*4], h1 = hist[tid*4+1], h2 = hist[tid*4+2], h3 = hist[tid*4+3];
            u32 loc = h0 + h1 + h2 + h3;
            u32 p = loc;
            #pragma unroll
            for (int o = 1; o < 64; o <<= 1) { u32 t2 = __shfl_up(p, o); if (lane >= o) p += t2; }
            u32 base = p - loc;
            hsc[tid*4]   = base + h0;
            hsc[tid*4+1] = base + h0 + h1;
            hsc[tid*4+2] = base + h0 + h1 + h2;
            hsc[tid*4+3] = base + h0 + h1 + h2 + h3;
        }
        __syncthreads();
        if (tid < 256) {
            u32 inc = hsc[tid], cb = inc - hist[tid];
            if (cb < r && r <= inc) { s_D = tid; s_rank = r - cb; }
        }
        __syncthreads();
        u32 D = s_D;
        // partition with STATIC-indexed register staging (no scratch)
        u64 vv[11]; bool vb[11];
        #pragma unroll
        for (int it = 0; it < 11; ++it) {
            u32 i = tid + it * 1024;
            vb[it] = (i < cn);
            vv[it] = vb[it] ? cand[i] : 0ULL;
        }
        __syncthreads();
        if (tid == 0) s_cand = 0;
        __syncthreads();
        #pragma unroll
        for (int it = 0; it < 11; ++it) {
            u32 dg = (u32)(vv[it] >> shift) & 0xFFu;
            bool tk = vb[it] && (dg < D);
            u64 bt = __ballot(tk);
            u32 base = 0;
            if (lane == 0 && bt) base = atomicAdd(&s_cnt, (u32)__popcll(bt));
            base = __shfl(base, 0);
            if (tk) sk[base + __popcll(bt & below)] = vv[it];
        }
        #pragma unroll
        for (int it = 0; it < 11; ++it) {
            u32 dg = (u32)(vv[it] >> shift) & 0xFFu;
            bool tk = vb[it] && (dg == D);
            u64 bt = __ballot(tk);
            u32 base = 0;
            if (lane == 0 && bt) base = atomicAdd(&s_cand, (u32)__popcll(bt));
            base = __shfl(base, 0);
            if (tk) cand[base + __popcll(bt & below)] = vv[it];
        }
        __syncthreads();
    }
    __syncthreads();

    // ---- hybrid bitonic sort 2048 keys ascending ----
    {
        int w = tid >> 6, l = lane;
        int base = w * 128;
        u64 a = sk[base + l], c = sk[base + 64 + l];
        #pragma unroll
        for (int k = 2; k <= 128; k <<= 1) {
            for (int j = k >> 1; j > 0; j >>= 1) {
                if (j == 64) {
                    bool dir = (((base + l) & k) == 0);
                    u64 lo = a < c ? a : c;
                    u64 hi = a < c ? c : a;
                    a = dir ? lo : hi;
                    c = dir ? hi : lo;
                } else {
                    bool up_ = (l & j) != 0;
                    bool dira = (((base + l) & k) == 0);
                    bool dirc = (((base + 64 + l) & k) == 0);
                    u64 pa = __shfl_xor(a, j);
                    u64 pc = __shfl_xor(c, j);
                    a = (up_ == dira) ? (a > pa ? a : pa) : (a < pa ? a : pa);
                    c = (up_ == dirc) ? (c > pc ? c : pc) : (c < pc ? c : pc);
                }
            }
        }
        sk[base + l] = a; sk[base + 64 + l] = c;
        __syncthreads();
        for (int k = 256; k <= NSEL; k <<= 1) {
            for (int j = k >> 1; j >= 128; j >>= 1) {
                int n = tid;
                int i = ((n & ~(j - 1)) << 1) | (n & (j - 1));
                int l2 = i | j;
                u64 x = sk[i], y = sk[l2];
                bool up2 = ((i & k) == 0);
                if ((x > y) == up2) { sk[i] = y; sk[l2] = x; }
                __syncthreads();
            }
            a = sk[base + l]; c = sk[base + 64 + l];
            bool dirk = ((base & k) == 0);
            {
                u64 lo = a < c ? a : c;
                u64 hi = a < c ? c : a;
                a = dirk ? lo : hi;
                c = dirk ? hi : lo;
            }
            #pragma unroll
            for (int j = 32; j > 0; j >>= 1) {
                bool up_ = (l & j) != 0;
                u64 pa = __shfl_xor(a, j);
                u64 pc = __shfl_xor(c, j);
                a = (up_ == dirk) ? (a > pa ? a : pa) : (a < pa ? a : pa);
                c = (up_ == dirk) ? (c > pc ? c : pc) : (c < pc ? c : pc);
            }
            sk[base + l] = a; sk[base + 64 + l] = c;
            __syncthreads();
        }
    }

    for (int i = tid; i < NSEL; i += 1024) gskey[(size_t)b * NSEL + i] = sk[i];
    if (tid < NWORD) gkeep[(size_t)b * NWORD + tid] = 0ULL;   // zero for k_cnms
}

// ---- Kernel 4: per-class NMS straight from gskey/boxes/cls ----
__global__ __launch_bounds__(1024) void k_cnms(const u64* __restrict__ gskey,
                                               const float4* __restrict__ boxes,
                                               const int* __restrict__ cls,
                                               u64* __restrict__ gkeep) {
    __shared__ u16 wmem[16][NSEL];    // 64 KB
    __shared__ u64 wkeep[16][NWORD];  // 4 KB

    int b = blockIdx.y;
    int cg = blockIdx.x;
    int lane = threadIdx.x & 63, wv = threadIdx.x >> 6;
    int c = cg * 16 + wv;
    const u64* KY = gskey + (size_t)b * NSEL;
    const float4* BX = boxes + (size_t)b * NANCH;
    const int* CL = cls + (size_t)b * NANCH;
    u64 below = (1ULL << lane) - 1ULL;
    float off = (float)c * MAXWH;    // wave-uniform class offset

    // build member list (ascending rank == descending score)
    int n = 0;
    for (int ch = 0; ch < NWORD; ++ch) {
        int i = ch * 64 + lane;
        u64 key = KY[i];
        bool valid = (key >> 63) == 0ULL;
        int a = (int)(key & 0xFFFFFFFFu);
        int ci = valid ? CL[a] : -1;
        bool pred = (ci == c);
        u64 bal = __ballot(pred);
        if (pred) wmem[wv][n + __popcll(bal & below)] = (u16)i;
        n += __popcll(bal);
    }

    for (int c0 = 0; c0 < n; c0 += 64) {
        int chunkn = n - c0; if (chunkn > 64) chunkn = 64;
        bool mv = lane < chunkn;
        int q = mv ? (int)wmem[wv][c0 + lane] : 0;
        int aq = (int)(KY[q] & 0xFFFFFFFFu);
        float4 b4 = BX[aq];
        float4 bq;
        bq.x = b4.x + off; bq.y = b4.y + off;
        bq.z = b4.z + off; bq.w = b4.w + off;
        float aqr = (bq.z - bq.x) * (bq.w - bq.y);

        // hit-test vs earlier kept members (only runs when n > 64)
        bool hit = false;
        for (int j = 0; j < c0; ++j) {
            if (!((wkeep[wv][j >> 6] >> (j & 63)) & 1ULL)) continue;
            int p = (int)wmem[wv][j];
            int ap = (int)(KY[p] & 0xFFFFFFFFu);
            float4 p4 = BX[ap];
            float4 bp;
            bp.x = p4.x + off; bp.y = p4.y + off;
            bp.z = p4.z + off; bp.w = p4.w + off;
            float apr = (bp.z - bp.x) * (bp.w - bp.y);
            float ltx = fmaxf(bp.x, bq.x), lty = fmaxf(bp.y, bq.y);
            float rbx = fminf(bp.z, bq.z), rby = fminf(bp.w, bq.w);
            float ww = fmaxf(rbx - ltx, 0.0f), hh = fmaxf(rby - lty, 0.0f);
            float inter = ww * hh;
            hit = hit || (mv && (inter / (apr + aqr - inter + 1e-16f) > NMS_T));
        }
        u64 avail = __ballot(mv && !hit);

        // within-chunk adjacency: lane t holds row t
        u64 Rt = 0;
        for (int t = 0; t < chunkn; ++t) {
            int p = (int)wmem[wv][c0 + t];
            int ap = (int)(KY[p] & 0xFFFFFFFFu);
            float4 p4 = BX[ap];
            float4 bp;
            bp.x = p4.x + off; bp.y = p4.y + off;
            bp.z = p4.z + off; bp.w = p4.w + off;
            float apr = (bp.z - bp.x) * (bp.w - bp.y);
            float ltx = fmaxf(bp.x, bq.x), lty = fmaxf(bp.y, bq.y);
            float rbx = fminf(bp.z, bq.z), rby = fminf(bp.w, bq.w);
            float ww = fmaxf(rbx - ltx, 0.0f), hh = fmaxf(rby - lty, 0.0f);
            float inter = ww * hh;
            u64 row = __ballot(mv && (inter / (apr + aqr - inter + 1e-16f) > NMS_T));
            if (lane == t) Rt = row;
        }

        // peel: greedy == lexicographically-first MIS (symmetric adjacency)
        u64 U = avail, kept = 0;
        while (U) {
            bool inU = ((U >> lane) & 1ULL) != 0ULL;
            u64 newk = __ballot(inU && ((Rt & U & below) == 0ULL));
            u64 killed = __ballot((Rt & newk) != 0ULL);
            kept |= newk;
            U &= ~(newk | killed);
        }
        if (lane == 0) wkeep[wv][c0 >> 6] = kept;
        if ((kept >> lane) & 1ULL)
            atomicOr(&gkeep[(size_t)b * NWORD + (q >> 6)], 1ULL << (q & 63));
    }
}

// ---- Kernel 5: compact kept entries (descending-score order) + zero fill ----
__global__ __launch_bounds__(64) void k_out(const u64* __restrict__ gkeep,
                                            const u64* __restrict__ gskey,
                                            const float4* __restrict__ boxes,
                                            const int* __restrict__ cls,
                                            float* __restrict__ out) {
    int b = blockIdx.x;
    int lane = threadIdx.x;
    const u64* KY = gskey + (size_t)b * NSEL;
    u64 kreg = (lane < NWORD) ? gkeep[(size_t)b * NWORD + lane] : 0ULL;

    int cnt = (lane < NWORD) ? __popcll(kreg) : 0;
    int pre = cnt;
    #pragma unroll
    for (int dd = 1; dd < 64; dd <<= 1) {
        int o = __shfl_up(pre, dd);
        if (lane >= dd) pre += o;
    }
    int total = __shfl(pre, 63);
    int base = pre - cnt;
    float* OUT = out + (size_t)b * MAXDET * 6;
    if (lane < NWORD) {
        u64 m = kreg;
        int rr = 0;
        while (m) {
            int t = __ffsll((long long)m) - 1;
            m &= m - 1;
            int slot = base + rr; ++rr;
            if (slot < MAXDET) {
                int i = lane * 64 + t;
                u64 key = KY[i];
                int a = (int)(key & 0xFFFFFFFFu);
                if ((unsigned)a >= NANCH) a = 0;   // fault-safe
                float4 bx = boxes[(size_t)b * NANCH + a];
                int c = cls[(size_t)b * NANCH + a];
                float sc = dec_score(key);
                float* o6 = OUT + slot * 6;
                o6[0] = bx.x; o6[1] = bx.y; o6[2] = bx.z; o6[3] = bx.w;
                o6[4] = sc; o6[5] = (float)c;
            }
        }
    }
    int start = total > MAXDET ? MAXDET : total;
    for (int s = start + lane; s < MAXDET; s += 64) {
        float* o6 = OUT + s * 6;
        o6[0] = 0.0f; o6[1] = 0.0f; o6[2] = 0.0f;
        o6[3] = 0.0f; o6[4] = 0.0f; o6[5] = 0.0f;
    }
}

// ---------------- Launcher (5 nodes) ----------------
extern "C" void kernel_launch(void* const* d_in, const int* in_sizes, int n_in,
                              void* d_out, int out_size, void* d_ws, size_t ws_size,
                              hipStream_t stream) {
    const float* pred = (const float*)d_in[0];
    float* out = (float*)d_out;

    char* ws = (char*)d_ws;
    size_t off = 0;
    auto alloc = [&](size_t bytes) -> void* {
        void* p = ws + off;
        off += (bytes + 255) & ~(size_t)255;
        return p;
    };

    u64*    keys   = (u64*)   alloc((size_t)NBATCH * NSORT * 8);
    float4* boxes  = (float4*)alloc((size_t)NBATCH * NANCH * 16);
    int*    cls    = (int*)   alloc((size_t)NBATCH * NANCH * 4);
    u32*    bhist  = (u32*)   alloc((size_t)NBATCH * NBLK1 * 256 * 4);
    u64*    gslice = (u64*)   alloc((size_t)NBATCH * 8 * PART * 8);
    uint2*  gpart  = (uint2*) alloc((size_t)NBATCH * 8 * 8);
    u64*    gskey  = (u64*)   alloc((size_t)NBATCH * NSEL * 8);
    u64*    gkeep  = (u64*)   alloc((size_t)NBATCH * NWORD * 8);

    dim3 g1(NBLK1, NBATCH);
    k_prep<<<g1, 256, 0, stream>>>(pred, keys, boxes, cls, bhist);

    dim3 g2(8, NBATCH);
    k_scan<<<g2, 1024, 0, stream>>>(keys, bhist, gslice, gpart);

    k_fin<<<NBATCH, 1024, 0, stream>>>(gslice, gpart, gskey, gkeep);

    dim3 g4(5, NBATCH);
    k_cnms<<<g4, 1024, 0, stream>>>(gskey, boxes, cls, gkeep);

    k_out<<<NBATCH, 64, 0, stream>>>(gkeep, gskey, boxes, cls, out);
}

// Round 19
// 103.004 us; speedup vs baseline: 1.1844x; 1.1844x over previous
//
#include <hip/hip_runtime.h>
#include <hip/hip_bf16.h>
#include <stdint.h>

typedef unsigned long long u64;
typedef unsigned int u32;
typedef unsigned short u16;

#define NANCH 10647
#define NBATCH 16
#define NSORT 16384
#define NSEL 2048
#define NWORD 32
#define NCLS 80
#define CONF_T 0.5f
#define NMS_T 0.5f
#define MAXDET 300
#define MAXWH 4096.0f
#define CANDCAP 10688   // >= NANCH, 64-aligned
#define PART 1344       // ceil(NANCH/8) rounded to 64
#define NBLK1 84        // (NANCH+127)/128

// exact inverse of the key's score mapping (bijective bit ops; r16/r18-verified)
__device__ __forceinline__ float dec_score(u64 key) {
    u32 v = ~(u32)(key >> 32);
    u32 u = (v & 0x80000000u) ? (v & 0x7FFFFFFFu) : ~v;
    return __uint_as_float(u);
}

// ---------------- Kernel 1: per-anchor prep (+ per-block top-byte hist) ----------------
__global__ __launch_bounds__(256) void k_prep(const float* __restrict__ pred,
                                              u64* __restrict__ keys,
                                              float4* __restrict__ boxes,
                                              int* __restrict__ cls,
                                              u32* __restrict__ bhist) {
    __shared__ float sm[128 * 85];
    __shared__ u32 ph[256];
    int b = blockIdx.y;
    int a0 = blockIdx.x * 128;
    int na = NANCH - a0; if (na > 128) na = 128;
    const float* src = pred + ((size_t)b * NANCH + a0) * 85;
    int tot = na * 85;
    ph[threadIdx.x] = 0;
    // 16B-aligned float4 staging (align-down + shift; r17-verified)
    {
        size_t srcaddr = (size_t)src;
        int shift = (int)((srcaddr & 15) >> 2);
        const float4* A = (const float4*)(srcaddr & ~(size_t)15);
        int nvec = (tot + shift + 3) >> 2;
        for (int j = threadIdx.x; j < nvec; j += 256) {
            float4 v = A[j];
            int base = 4 * j - shift;
            if (base >= 0 && base + 3 < tot) {
                sm[base] = v.x; sm[base + 1] = v.y;
                sm[base + 2] = v.z; sm[base + 3] = v.w;
            } else {
                if (base >= 0 && base < tot)         sm[base]     = v.x;
                if (base + 1 >= 0 && base + 1 < tot) sm[base + 1] = v.y;
                if (base + 2 >= 0 && base + 2 < tot) sm[base + 2] = v.z;
                if (base + 3 >= 0 && base + 3 < tot) sm[base + 3] = v.w;
            }
        }
    }
    __syncthreads();
    int t = threadIdx.x;
    u64 kk = 0;
    if (t < na) {
        const float* s = &sm[t * 85];
        float x = s[0], y = s[1], w = s[2], h = s[3], obj = s[4];
        float best = s[5] * obj; int arg = 0;
        #pragma unroll
        for (int c = 1; c < 80; ++c) {
            float v = s[5 + c] * obj;
            if (v > best) { best = v; arg = c; }
        }
        bool valid = obj >= CONF_T;
        float sc = valid ? best : -1.0f;
        int a = a0 + t;
        float4 bx;
        bx.x = x - w * 0.5f; bx.y = y - h * 0.5f;
        bx.z = x + w * 0.5f; bx.w = y + h * 0.5f;
        size_t o = (size_t)b * NANCH + a;
        boxes[o] = bx;
        cls[o] = arg;
        u32 u = __float_as_uint(sc);
        u32 v = (u & 0x80000000u) ? ~u : (u | 0x80000000u); // ascending map
        u32 hi = ~v;                                        // descending
        kk = ((u64)hi << 32) | (u32)a;
        keys[(size_t)b * NSORT + a] = kk;
    }
    // wave-aggregated 256-bin histogram of key top byte (block-local)
    u32 bin = (t < na) ? (u32)(kk >> 56) : 0xFFFFFFFFu;
    int lane = t & 63;
    u64 rem = __ballot(t < na);
    while (rem) {
        int srcl = __ffsll((long long)rem) - 1;
        u32 lb = __shfl(bin, srcl);
        u64 same = __ballot(bin == lb) & rem;
        if (lane == srcl) atomicAdd(&ph[lb], (u32)__popcll(same));
        rem &= ~same;
    }
    __syncthreads();
    bhist[(((size_t)b * NBLK1) + blockIdx.x) * 256 + threadIdx.x] = ph[threadIdx.x];
}

// ---- Kernel 2: deterministic classify scan -> partition slices (no atomics) ----
__global__ __launch_bounds__(1024) void k_scan(const u64* __restrict__ keys,
                                               const u32* __restrict__ bhist,
                                               u64* __restrict__ gslice,
                                               uint2* __restrict__ gpart) {
    __shared__ u32 hist[256];
    __shared__ u32 hsc[256];
    __shared__ u32 s_D0;
    __shared__ u32 wcs[16], wcc[16];
    __shared__ u32 s_tc;
    int b = blockIdx.y;
    int part = blockIdx.x;
    int tid = threadIdx.x;
    int lane = tid & 63, wv = tid >> 6;
    u64 below = (1ULL << lane) - 1ULL;
    const u64* KB = keys + (size_t)b * NSORT;

    if (tid < 256) {
        u32 h = 0;
        const u32* BH = bhist + (size_t)b * NBLK1 * 256 + tid;
        for (int j = 0; j < NBLK1; ++j) h += BH[(size_t)j * 256];
        hist[tid] = h;
    }
    __syncthreads();
    if (tid < 64) {
        u32 h0 = hist[tid*4], h1 = hist[tid*4+1], h2 = hist[tid*4+2], h3 = hist[tid*4+3];
        u32 loc = h0 + h1 + h2 + h3;
        u32 p = loc;
        #pragma unroll
        for (int o = 1; o < 64; o <<= 1) { u32 t2 = __shfl_up(p, o); if (lane >= o) p += t2; }
        u32 base = p - loc;
        hsc[tid*4]   = base + h0;
        hsc[tid*4+1] = base + h0 + h1;
        hsc[tid*4+2] = base + h0 + h1 + h2;
        hsc[tid*4+3] = base + h0 + h1 + h2 + h3;
    }
    __syncthreads();
    if (tid < 256) {
        u32 inc = hsc[tid], cb = inc - hist[tid];
        if (cb < NSEL && NSEL <= inc) s_D0 = tid;
    }
    __syncthreads();
    u32 D0 = s_D0;

    u64 kk0 = 0, kk1 = 0;
    bool s0 = false, s1 = false, c0 = false, c1 = false;
    {
        int off = tid, i = part * PART + off;
        bool inb = (off < PART) && (i < NANCH);
        kk0 = inb ? KB[i] : 0ULL;
        u32 top = (u32)(kk0 >> 56);
        s0 = inb && (top < D0); c0 = inb && (top == D0);
    }
    {
        int off = 1024 + tid, i = part * PART + off;
        bool inb = (off < PART) && (i < NANCH);
        kk1 = inb ? KB[i] : 0ULL;
        u32 top = (u32)(kk1 >> 56);
        s1 = inb && (top < D0); c1 = inb && (top == D0);
    }
    u64 bs0 = __ballot(s0), bs1 = __ballot(s1);
    u64 bc0 = __ballot(c0), bc1 = __ballot(c1);
    if (lane == 0) {
        wcs[wv] = (u32)(__popcll(bs0) + __popcll(bs1));
        wcc[wv] = (u32)(__popcll(bc0) + __popcll(bc1));
    }
    __syncthreads();
    if (tid < 16) {
        u32 vs = wcs[tid], vc = wcc[tid];
        u32 ps = vs, pc = vc;
        #pragma unroll
        for (int o = 1; o < 16; o <<= 1) {
            u32 ts = __shfl_up(ps, o);
            u32 tc = __shfl_up(pc, o);
            if (tid >= o) { ps += ts; pc += tc; }
        }
        wcs[tid] = ps - vs;   // exclusive wave base
        wcc[tid] = pc - vc;
        if (tid == 15) {
            s_tc = pc;
            gpart[(size_t)b * 8 + part] = make_uint2(ps, pc);  // totals
        }
    }
    __syncthreads();
    u64* SL = gslice + ((size_t)b * 8 + part) * (size_t)PART;
    u32 base_s = wcs[wv];
    u32 base_c = (u32)PART - s_tc + wcc[wv];
    if (s0) SL[base_s + __popcll(bs0 & below)] = kk0;
    if (s1) SL[base_s + __popcll(bs0) + __popcll(bs1 & below)] = kk1;
    if (c0) SL[base_c + __popcll(bc0 & below)] = kk0;
    if (c1) SL[base_c + __popcll(bc0) + __popcll(bc1 & below)] = kk1;
}

// ---- Kernel 3: compact slices + refine threshold + hybrid bitonic -> gskey ----
// Invariant: s_cnt + s_rank == NSEL at every refine-loop entry.
__global__ __launch_bounds__(1024) void k_fin(const u64* __restrict__ gslice,
                                              const uint2* __restrict__ gpart,
                                              u64* __restrict__ gskey,
                                              u64* __restrict__ gkeep) {
    __shared__ u64 sk[NSEL];        // 16 KB
    __shared__ u64 cand[CANDCAP];   // 85.5 KB
    __shared__ u32 hist[256];
    __shared__ u32 hsc[256];
    __shared__ u64 s_red[16];
    __shared__ u32 ssA[8], ccA[8], soff[9], coff[9];
    __shared__ u32 s_D, s_rank, s_cnt, s_cand;

    int b = blockIdx.x;
    int tid = threadIdx.x;
    int lane = tid & 63;
    u64 below = (1ULL << lane) - 1ULL;

    if (tid < 8) { uint2 v = gpart[(size_t)b * 8 + tid]; ssA[tid] = v.x; ccA[tid] = v.y; }
    for (int i = tid; i < NSEL; i += 1024) sk[i] = ~0ULL;   // safety fill
    __syncthreads();
    if (tid == 0) {
        u32 a = 0, c2 = 0;
        for (int j = 0; j < 8; ++j) { soff[j] = a; a += ssA[j]; coff[j] = c2; c2 += ccA[j]; }
        soff[8] = a; coff[8] = c2;
        s_cnt = a; s_rank = NSEL - a; s_cand = c2;
    }
    __syncthreads();
    for (int j = 0; j < 8; ++j) {
        const u64* SL = gslice + ((size_t)b * 8 + j) * (size_t)PART;
        u32 ns = ssA[j], nc = ccA[j];
        u32 so = soff[j], co = coff[j];
        for (u32 i = tid; i < ns; i += 1024) sk[so + i] = SL[i];
        for (u32 i = tid; i < nc; i += 1024) cand[co + i] = SL[PART - nc + i];
    }
    __syncthreads();

    // ---- refine within cand; append sure-members to sk each round ----
    const int shifts2[5] = {48, 40, 32, 8, 0};
    for (int rr = 0; ; ++rr) {
        u32 cn = s_cand, r = s_rank;
        if (r == cn || rr == 5) {
            for (u32 i0 = 0; i0 < cn; i0 += 1024) {
                u32 i = i0 + tid;
                bool take = i < cn;
                u64 kk = take ? cand[i] : 0ULL;
                u64 bt = __ballot(take);
                u32 base = 0;
                if (lane == 0 && bt) base = atomicAdd(&s_cnt, (u32)__popcll(bt));
                base = __shfl(base, 0);
                if (take) sk[base + __popcll(bt & below)] = kk;
            }
            break;
        }
        if (r == 1) {
            u64 best = ~0ULL;
            for (u32 i = tid; i < cn; i += 1024) { u64 kk = cand[i]; if (kk < best) best = kk; }
            #pragma unroll
            for (int o = 32; o > 0; o >>= 1) {
                u64 other = __shfl_down(best, o);
                if (other < best) best = other;
            }
            if (lane == 0) s_red[tid >> 6] = best;
            __syncthreads();
            if (tid == 0) {
                u64 m = s_red[0];
                for (int w2 = 1; w2 < 16; ++w2) if (s_red[w2] < m) m = s_red[w2];
                sk[atomicAdd(&s_cnt, 1u)] = m;
            }
            break;
        }
        int shift = shifts2[rr];
        if (tid < 256) hist[tid] = 0;
        __syncthreads();
        for (u32 i = tid; i < cn; i += 1024)
            atomicAdd(&hist[(u32)(cand[i] >> shift) & 0xFFu], 1u);
        __syncthreads();
        if (tid < 64) {
            u32 h0 = hist[tid*4], h1 = hist[tid*4+1], h2 = hist[tid*4+2], h3 = hist[tid*4+3];
            u32 loc = h0 + h1 + h2 + h3;
            u32 p = loc;
            #pragma unroll
            for (int o = 1; o < 64; o <<= 1) { u32 t2 = __shfl_up(p, o); if (lane >= o) p += t2; }
            u32 base = p - loc;
            hsc[tid*4]   = base + h0;
            hsc[tid*4+1] = base + h0 + h1;
            hsc[tid*4+2] = base + h0 + h1 + h2;
            hsc[tid*4+3] = base + h0 + h1 + h2 + h3;
        }
        __syncthreads();
        if (tid < 256) {
            u32 inc = hsc[tid], cb = inc - hist[tid];
            if (cb < r && r <= inc) { s_D = tid; s_rank = r - cb; }
        }
        __syncthreads();
        u32 D = s_D;
        // partition with STATIC-indexed register staging (no scratch)
        u64 vv[11]; bool vb[11];
        #pragma unroll
        for (int it = 0; it < 11; ++it) {
            u32 i = tid + it * 1024;
            vb[it] = (i < cn);
            vv[it] = vb[it] ? cand[i] : 0ULL;
        }
        __syncthreads();
        if (tid == 0) s_cand = 0;
        __syncthreads();
        #pragma unroll
        for (int it = 0; it < 11; ++it) {
            u32 dg = (u32)(vv[it] >> shift) & 0xFFu;
            bool tk = vb[it] && (dg < D);
            u64 bt = __ballot(tk);
            u32 base = 0;
            if (lane == 0 && bt) base = atomicAdd(&s_cnt, (u32)__popcll(bt));
            base = __shfl(base, 0);
            if (tk) sk[base + __popcll(bt & below)] = vv[it];
        }
        #pragma unroll
        for (int it = 0; it < 11; ++it) {
            u32 dg = (u32)(vv[it] >> shift) & 0xFFu;
            bool tk = vb[it] && (dg == D);
            u64 bt = __ballot(tk);
            u32 base = 0;
            if (lane == 0 && bt) base = atomicAdd(&s_cand, (u32)__popcll(bt));
            base = __shfl(base, 0);
            if (tk) cand[base + __popcll(bt & below)] = vv[it];
        }
        __syncthreads();
    }
    __syncthreads();

    // ---- hybrid bitonic sort 2048 keys ascending ----
    {
        int w = tid >> 6, l = lane;
        int base = w * 128;
        u64 a = sk[base + l], c = sk[base + 64 + l];
        #pragma unroll
        for (int k = 2; k <= 128; k <<= 1) {
            for (int j = k >> 1; j > 0; j >>= 1) {
                if (j == 64) {
                    bool dir = (((base + l) & k) == 0);
                    u64 lo = a < c ? a : c;
                    u64 hi = a < c ? c : a;
                    a = dir ? lo : hi;
                    c = dir ? hi : lo;
                } else {
                    bool up_ = (l & j) != 0;
                    bool dira = (((base + l) & k) == 0);
                    bool dirc = (((base + 64 + l) & k) == 0);
                    u64 pa = __shfl_xor(a, j);
                    u64 pc = __shfl_xor(c, j);
                    a = (up_ == dira) ? (a > pa ? a : pa) : (a < pa ? a : pa);
                    c = (up_ == dirc) ? (c > pc ? c : pc) : (c < pc ? c : pc);
                }
            }
        }
        sk[base + l] = a; sk[base + 64 + l] = c;
        __syncthreads();
        for (int k = 256; k <= NSEL; k <<= 1) {
            for (int j = k >> 1; j >= 128; j >>= 1) {
                int n = tid;
                int i = ((n & ~(j - 1)) << 1) | (n & (j - 1));
                int l2 = i | j;
                u64 x = sk[i], y = sk[l2];
                bool up2 = ((i & k) == 0);
                if ((x > y) == up2) { sk[i] = y; sk[l2] = x; }
                __syncthreads();
            }
            a = sk[base + l]; c = sk[base + 64 + l];
            bool dirk = ((base & k) == 0);
            {
                u64 lo = a < c ? a : c;
                u64 hi = a < c ? c : a;
                a = dirk ? lo : hi;
                c = dirk ? hi : lo;
            }
            #pragma unroll
            for (int j = 32; j > 0; j >>= 1) {
                bool up_ = (l & j) != 0;
                u64 pa = __shfl_xor(a, j);
                u64 pc = __shfl_xor(c, j);
                a = (up_ == dirk) ? (a > pa ? a : pa) : (a < pa ? a : pa);
                c = (up_ == dirk) ? (c > pc ? c : pc) : (c < pc ? c : pc);
            }
            sk[base + l] = a; sk[base + 64 + l] = c;
            __syncthreads();
        }
    }

    for (int i = tid; i < NSEL; i += 1024) gskey[(size_t)b * NSEL + i] = sk[i];
    if (tid < NWORD) gkeep[(size_t)b * NWORD + tid] = 0ULL;   // zero for k_cnms
}

// ---- Kernel 4: parallel gather (one rank per thread, 128 blocks) ----
__global__ __launch_bounds__(256) void k_gather(const u64* __restrict__ gskey,
                                                const float4* __restrict__ boxes,
                                                const int* __restrict__ cls,
                                                float4* __restrict__ sel_box,
                                                float4* __restrict__ sel_sbox,
                                                float* __restrict__ sel_area,
                                                float* __restrict__ sel_score,
                                                int* __restrict__ sel_cls) {
    int b = blockIdx.y;
    int r = blockIdx.x * 256 + threadIdx.x;
    u64 key = gskey[(size_t)b * NSEL + r];
    int a = (int)(key & 0xFFFFFFFFu);
    if ((unsigned)a >= NANCH) a = 0;   // fault-safe
    size_t src = (size_t)b * NANCH + a;
    float4 bx = boxes[src];
    int c = cls[src];
    float sc = dec_score(key);
    float off = (float)c * MAXWH;
    float4 sb;
    sb.x = bx.x + off; sb.y = bx.y + off;
    sb.z = bx.z + off; sb.w = bx.w + off;
    float area = (sb.z - sb.x) * (sb.w - sb.y);
    size_t o = (size_t)b * NSEL + r;
    sel_box[o] = bx; sel_sbox[o] = sb; sel_area[o] = area;
    sel_score[o] = sc; sel_cls[o] = c;
}

// ---- Kernel 5: per-class NMS (IoU matrix is block-diagonal by class) ----
__global__ __launch_bounds__(1024) void k_cnms(const float4* __restrict__ sel_sbox,
                                               const float* __restrict__ sel_area,
                                               const int* __restrict__ sel_cls,
                                               const float* __restrict__ sel_score,
                                               u64* __restrict__ gkeep) {
    __shared__ u16 wmem[16][NSEL];    // 64 KB
    __shared__ u64 wkeep[16][NWORD];  // 4 KB

    int b = blockIdx.y;
    int cg = blockIdx.x;
    int lane = threadIdx.x & 63, wv = threadIdx.x >> 6;
    int c = cg * 16 + wv;
    size_t bb = (size_t)b * NSEL;
    const int* CL = sel_cls + bb;
    const float* SC = sel_score + bb;
    u64 below = (1ULL << lane) - 1ULL;

    int n = 0;
    for (int ch = 0; ch < NWORD; ++ch) {
        int i = ch * 64 + lane;
        bool pred = (CL[i] == c) && (SC[i] >= 0.0f);
        u64 bal = __ballot(pred);
        if (pred) wmem[wv][n + __popcll(bal & below)] = (u16)i;
        n += __popcll(bal);
    }

    for (int c0 = 0; c0 < n; c0 += 64) {
        int chunkn = n - c0; if (chunkn > 64) chunkn = 64;
        bool mv = lane < chunkn;
        int q = mv ? (int)wmem[wv][c0 + lane] : 0;
        float4 bq = sel_sbox[bb + q];
        float aq = sel_area[bb + q];

        bool hit = false;
        for (int j = 0; j < c0; ++j) {
            if (!((wkeep[wv][j >> 6] >> (j & 63)) & 1ULL)) continue;
            int p = (int)wmem[wv][j];
            float4 bp = sel_sbox[bb + p];
            float ap = sel_area[bb + p];
            float ltx = fmaxf(bp.x, bq.x), lty = fmaxf(bp.y, bq.y);
            float rbx = fminf(bp.z, bq.z), rby = fminf(bp.w, bq.w);
            float ww = fmaxf(rbx - ltx, 0.0f), hh = fmaxf(rby - lty, 0.0f);
            float inter = ww * hh;
            hit = hit || (mv && (inter / (ap + aq - inter + 1e-16f) > NMS_T));
        }
        u64 avail = __ballot(mv && !hit);

        u64 Rt = 0;
        for (int t = 0; t < chunkn; ++t) {
            int p = (int)wmem[wv][c0 + t];
            float4 bp = sel_sbox[bb + p];
            float ap = sel_area[bb + p];
            float ltx = fmaxf(bp.x, bq.x), lty = fmaxf(bp.y, bq.y);
            float rbx = fminf(bp.z, bq.z), rby = fminf(bp.w, bq.w);
            float ww = fmaxf(rbx - ltx, 0.0f), hh = fmaxf(rby - lty, 0.0f);
            float inter = ww * hh;
            u64 row = __ballot(mv && (inter / (ap + aq - inter + 1e-16f) > NMS_T));
            if (lane == t) Rt = row;
        }

        u64 U = avail, kept = 0;
        while (U) {
            bool inU = ((U >> lane) & 1ULL) != 0ULL;
            u64 newk = __ballot(inU && ((Rt & U & below) == 0ULL));
            u64 killed = __ballot((Rt & newk) != 0ULL);
            kept |= newk;
            U &= ~(newk | killed);
        }
        if (lane == 0) wkeep[wv][c0 >> 6] = kept;
        if ((kept >> lane) & 1ULL)
            atomicOr(&gkeep[(size_t)b * NWORD + (q >> 6)], 1ULL << (q & 63));
    }
}

// ---- Kernel 6: compact kept entries (descending-score order) + zero fill ----
__global__ __launch_bounds__(64) void k_out(const u64* __restrict__ gkeep,
                                            const float4* __restrict__ sel_box,
                                            const float* __restrict__ sel_score,
                                            const int* __restrict__ sel_cls,
                                            float* __restrict__ out) {
    int b = blockIdx.x;
    int lane = threadIdx.x;
    const float* SC = sel_score + (size_t)b * NSEL;
    u64 kreg = (lane < NWORD) ? gkeep[(size_t)b * NWORD + lane] : 0ULL;

    int cnt = (lane < NWORD) ? __popcll(kreg) : 0;
    int pre = cnt;
    #pragma unroll
    for (int dd = 1; dd < 64; dd <<= 1) {
        int o = __shfl_up(pre, dd);
        if (lane >= dd) pre += o;
    }
    int total = __shfl(pre, 63);
    int base = pre - cnt;
    float* OUT = out + (size_t)b * MAXDET * 6;
    if (lane < NWORD) {
        u64 m = kreg;
        int rr = 0;
        while (m) {
            int t = __ffsll((long long)m) - 1;
            m &= m - 1;
            int slot = base + rr; ++rr;
            if (slot < MAXDET) {
                int i = lane * 64 + t;
                size_t src = (size_t)b * NSEL + i;
                float4 bx = sel_box[src];
                float sc = SC[i];
                int c = sel_cls[src];
                float* o6 = OUT + slot * 6;
                o6[0] = bx.x; o6[1] = bx.y; o6[2] = bx.z; o6[3] = bx.w;
                o6[4] = sc; o6[5] = (float)c;
            }
        }
    }
    int start = total > MAXDET ? MAXDET : total;
    for (int s = start + lane; s < MAXDET; s += 64) {
        float* o6 = OUT + s * 6;
        o6[0] = 0.0f; o6[1] = 0.0f; o6[2] = 0.0f;
        o6[3] = 0.0f; o6[4] = 0.0f; o6[5] = 0.0f;
    }
}

// ---------------- Launcher (6 nodes) ----------------
extern "C" void kernel_launch(void* const* d_in, const int* in_sizes, int n_in,
                              void* d_out, int out_size, void* d_ws, size_t ws_size,
                              hipStream_t stream) {
    const float* pred = (const float*)d_in[0];
    float* out = (float*)d_out;

    char* ws = (char*)d_ws;
    size_t off = 0;
    auto alloc = [&](size_t bytes) -> void* {
        void* p = ws + off;
        off += (bytes + 255) & ~(size_t)255;
        return p;
    };

    u64*    keys      = (u64*)   alloc((size_t)NBATCH * NSORT * 8);
    float4* boxes     = (float4*)alloc((size_t)NBATCH * NANCH * 16);
    int*    cls       = (int*)   alloc((size_t)NBATCH * NANCH * 4);
    u32*    bhist     = (u32*)   alloc((size_t)NBATCH * NBLK1 * 256 * 4);
    u64*    gslice    = (u64*)   alloc((size_t)NBATCH * 8 * PART * 8);
    uint2*  gpart     = (uint2*) alloc((size_t)NBATCH * 8 * 8);
    u64*    gskey     = (u64*)   alloc((size_t)NBATCH * NSEL * 8);
    u64*    gkeep     = (u64*)   alloc((size_t)NBATCH * NWORD * 8);
    float4* sel_box   = (float4*)alloc((size_t)NBATCH * NSEL * 16);
    float4* sel_sbox  = (float4*)alloc((size_t)NBATCH * NSEL * 16);
    float*  sel_area  = (float*) alloc((size_t)NBATCH * NSEL * 4);
    float*  sel_score = (float*) alloc((size_t)NBATCH * NSEL * 4);
    int*    sel_cls   = (int*)   alloc((size_t)NBATCH * NSEL * 4);

    dim3 g1(NBLK1, NBATCH);
    k_prep<<<g1, 256, 0, stream>>>(pred, keys, boxes, cls, bhist);

    dim3 g2(8, NBATCH);
    k_scan<<<g2, 1024, 0, stream>>>(keys, bhist, gslice, gpart);

    k_fin<<<NBATCH, 1024, 0, stream>>>(gslice, gpart, gskey, gkeep);

    dim3 g4(8, NBATCH);
    k_gather<<<g4, 256, 0, stream>>>(gskey, boxes, cls,
                                     sel_box, sel_sbox, sel_area,
                                     sel_score, sel_cls);

    dim3 g5(5, NBATCH);
    k_cnms<<<g5, 1024, 0, stream>>>(sel_sbox, sel_area, sel_cls, sel_score, gkeep);

    k_out<<<NBATCH, 64, 0, stream>>>(gkeep, sel_box, sel_score, sel_cls, out);
}

// Round 20
// 100.461 us; speedup vs baseline: 1.2144x; 1.0253x over previous
//
#include <hip/hip_runtime.h>
#include <hip/hip_bf16.h>
#include <stdint.h>

typedef unsigned long long u64;
typedef unsigned int u32;
typedef unsigned short u16;

#define NANCH 10647
#define NBATCH 16
#define NSORT 16384
#define NSEL 2048
#define NWORD 32
#define NCLS 80
#define CONF_T 0.5f
#define NMS_T 0.5f
#define MAXDET 300
#define MAXWH 4096.0f
#define CANDCAP 10688   // >= NANCH, 64-aligned
#define PART 1344       // ceil(NANCH/8) rounded to 64
#define NBLK1 84        // (NANCH+127)/128

// exact inverse of the key's score mapping (bijective bit ops; r16/r18-verified)
__device__ __forceinline__ float dec_score(u64 key) {
    u32 v = ~(u32)(key >> 32);
    u32 u = (v & 0x80000000u) ? (v & 0x7FFFFFFFu) : ~v;
    return __uint_as_float(u);
}

// ---------------- Kernel 1: per-anchor prep (+ per-block top-byte hist) ----------------
__global__ __launch_bounds__(256) void k_prep(const float* __restrict__ pred,
                                              u64* __restrict__ keys,
                                              float4* __restrict__ boxes,
                                              int* __restrict__ cls,
                                              u32* __restrict__ bhist,
                                              u32* __restrict__ ghist2) {
    __shared__ float sm[128 * 85];
    __shared__ u32 ph[256];
    int b = blockIdx.y;
    if (blockIdx.x == 0) ghist2[(size_t)b * 256 + threadIdx.x] = 0;   // zero for k_scan
    int a0 = blockIdx.x * 128;
    int na = NANCH - a0; if (na > 128) na = 128;
    const float* src = pred + ((size_t)b * NANCH + a0) * 85;
    int tot = na * 85;
    ph[threadIdx.x] = 0;
    // 16B-aligned float4 staging (align-down + shift; r17-verified)
    {
        size_t srcaddr = (size_t)src;
        int shift = (int)((srcaddr & 15) >> 2);
        const float4* A = (const float4*)(srcaddr & ~(size_t)15);
        int nvec = (tot + shift + 3) >> 2;
        for (int j = threadIdx.x; j < nvec; j += 256) {
            float4 v = A[j];
            int base = 4 * j - shift;
            if (base >= 0 && base + 3 < tot) {
                sm[base] = v.x; sm[base + 1] = v.y;
                sm[base + 2] = v.z; sm[base + 3] = v.w;
            } else {
                if (base >= 0 && base < tot)         sm[base]     = v.x;
                if (base + 1 >= 0 && base + 1 < tot) sm[base + 1] = v.y;
                if (base + 2 >= 0 && base + 2 < tot) sm[base + 2] = v.z;
                if (base + 3 >= 0 && base + 3 < tot) sm[base + 3] = v.w;
            }
        }
    }
    __syncthreads();
    int t = threadIdx.x;
    u64 kk = 0;
    if (t < na) {
        const float* s = &sm[t * 85];
        float x = s[0], y = s[1], w = s[2], h = s[3], obj = s[4];
        float best = s[5] * obj; int arg = 0;
        #pragma unroll
        for (int c = 1; c < 80; ++c) {
            float v = s[5 + c] * obj;
            if (v > best) { best = v; arg = c; }
        }
        bool valid = obj >= CONF_T;
        float sc = valid ? best : -1.0f;
        int a = a0 + t;
        float4 bx;
        bx.x = x - w * 0.5f; bx.y = y - h * 0.5f;
        bx.z = x + w * 0.5f; bx.w = y + h * 0.5f;
        size_t o = (size_t)b * NANCH + a;
        boxes[o] = bx;
        cls[o] = arg;
        u32 u = __float_as_uint(sc);
        u32 v = (u & 0x80000000u) ? ~u : (u | 0x80000000u); // ascending map
        u32 hi = ~v;                                        // descending
        kk = ((u64)hi << 32) | (u32)a;
        keys[(size_t)b * NSORT + a] = kk;
    }
    // wave-aggregated 256-bin histogram of key top byte (block-local)
    u32 bin = (t < na) ? (u32)(kk >> 56) : 0xFFFFFFFFu;
    int lane = t & 63;
    u64 rem = __ballot(t < na);
    while (rem) {
        int srcl = __ffsll((long long)rem) - 1;
        u32 lb = __shfl(bin, srcl);
        u64 same = __ballot(bin == lb) & rem;
        if (lane == srcl) atomicAdd(&ph[lb], (u32)__popcll(same));
        rem &= ~same;
    }
    __syncthreads();
    bhist[(((size_t)b * NBLK1) + blockIdx.x) * 256 + threadIdx.x] = ph[threadIdx.x];
}

// ---- Kernel 2: deterministic classify scan -> partition slices (no data atomics)
//      + global second-byte (shift 48) histogram of boundary keys ----
__global__ __launch_bounds__(1024) void k_scan(const u64* __restrict__ keys,
                                               const u32* __restrict__ bhist,
                                               u64* __restrict__ gslice,
                                               uint2* __restrict__ gpart,
                                               u32* __restrict__ ghist2) {
    __shared__ u32 hist[256];
    __shared__ u32 hsc[256];
    __shared__ u32 ph2[256];
    __shared__ u32 s_D0;
    __shared__ u32 wcs[16], wcc[16];
    __shared__ u32 s_tc;
    int b = blockIdx.y;
    int part = blockIdx.x;
    int tid = threadIdx.x;
    int lane = tid & 63, wv = tid >> 6;
    u64 below = (1ULL << lane) - 1ULL;
    const u64* KB = keys + (size_t)b * NSORT;

    if (tid < 256) {
        ph2[tid] = 0;
        u32 h = 0;
        const u32* BH = bhist + (size_t)b * NBLK1 * 256 + tid;
        for (int j = 0; j < NBLK1; ++j) h += BH[(size_t)j * 256];
        hist[tid] = h;
    }
    __syncthreads();
    if (tid < 64) {
        u32 h0 = hist[tid*4], h1 = hist[tid*4+1], h2 = hist[tid*4+2], h3 = hist[tid*4+3];
        u32 loc = h0 + h1 + h2 + h3;
        u32 p = loc;
        #pragma unroll
        for (int o = 1; o < 64; o <<= 1) { u32 t2 = __shfl_up(p, o); if (lane >= o) p += t2; }
        u32 base = p - loc;
        hsc[tid*4]   = base + h0;
        hsc[tid*4+1] = base + h0 + h1;
        hsc[tid*4+2] = base + h0 + h1 + h2;
        hsc[tid*4+3] = base + h0 + h1 + h2 + h3;
    }
    __syncthreads();
    if (tid < 256) {
        u32 inc = hsc[tid], cb = inc - hist[tid];
        if (cb < NSEL && NSEL <= inc) s_D0 = tid;
    }
    __syncthreads();
    u32 D0 = s_D0;

    u64 kk0 = 0, kk1 = 0;
    bool s0 = false, s1 = false, c0 = false, c1 = false;
    {
        int off = tid, i = part * PART + off;
        bool inb = (off < PART) && (i < NANCH);
        kk0 = inb ? KB[i] : 0ULL;
        u32 top = (u32)(kk0 >> 56);
        s0 = inb && (top < D0); c0 = inb && (top == D0);
    }
    {
        int off = 1024 + tid, i = part * PART + off;
        bool inb = (off < PART) && (i < NANCH);
        kk1 = inb ? KB[i] : 0ULL;
        u32 top = (u32)(kk1 >> 56);
        s1 = inb && (top < D0); c1 = inb && (top == D0);
    }
    // second-byte histogram of boundary keys (LDS private, flushed at end)
    if (c0) atomicAdd(&ph2[(u32)(kk0 >> 48) & 0xFFu], 1u);
    if (c1) atomicAdd(&ph2[(u32)(kk1 >> 48) & 0xFFu], 1u);
    u64 bs0 = __ballot(s0), bs1 = __ballot(s1);
    u64 bc0 = __ballot(c0), bc1 = __ballot(c1);
    if (lane == 0) {
        wcs[wv] = (u32)(__popcll(bs0) + __popcll(bs1));
        wcc[wv] = (u32)(__popcll(bc0) + __popcll(bc1));
    }
    __syncthreads();
    if (tid < 16) {
        u32 vs = wcs[tid], vc = wcc[tid];
        u32 ps = vs, pc = vc;
        #pragma unroll
        for (int o = 1; o < 16; o <<= 1) {
            u32 ts = __shfl_up(ps, o);
            u32 tc = __shfl_up(pc, o);
            if (tid >= o) { ps += ts; pc += tc; }
        }
        wcs[tid] = ps - vs;   // exclusive wave base
        wcc[tid] = pc - vc;
        if (tid == 15) {
            s_tc = pc;
            gpart[(size_t)b * 8 + part] = make_uint2(ps, pc);  // totals
        }
    }
    __syncthreads();
    u64* SL = gslice + ((size_t)b * 8 + part) * (size_t)PART;
    u32 base_s = wcs[wv];
    u32 base_c = (u32)PART - s_tc + wcc[wv];
    if (s0) SL[base_s + __popcll(bs0 & below)] = kk0;
    if (s1) SL[base_s + __popcll(bs0) + __popcll(bs1 & below)] = kk1;
    if (c0) SL[base_c + __popcll(bc0 & below)] = kk0;
    if (c1) SL[base_c + __popcll(bc0) + __popcll(bc1 & below)] = kk1;
    if (tid < 256 && ph2[tid]) atomicAdd(&ghist2[(size_t)b * 256 + tid], ph2[tid]);
}

// ---- Kernel 3: fused filtered load (round-0 partition via ghist2) +
//      refine (shift 40..0) + hybrid bitonic -> gskey ----
// Invariant: s_cnt + s_rank == NSEL at every refine-loop entry.
__global__ __launch_bounds__(1024) void k_fin(const u64* __restrict__ gslice,
                                              const uint2* __restrict__ gpart,
                                              const u32* __restrict__ ghist2,
                                              u64* __restrict__ gskey,
                                              u64* __restrict__ gkeep) {
    __shared__ u64 sk[NSEL];        // 16 KB
    __shared__ u64 cand[CANDCAP];   // 85.5 KB
    __shared__ u32 hist[256];
    __shared__ u32 hsc[256];
    __shared__ u64 s_red[16];
    __shared__ u32 ssA[8], ccA[8];
    __shared__ u32 s_D, s_r0, s_rank, s_cnt, s_cand;

    int b = blockIdx.x;
    int tid = threadIdx.x;
    int lane = tid & 63, wv = tid >> 6;
    u64 below = (1ULL << lane) - 1ULL;

    if (tid < 8) { uint2 v = gpart[(size_t)b * 8 + tid]; ssA[tid] = v.x; ccA[tid] = v.y; }
    if (tid < 256) hist[tid] = ghist2[(size_t)b * 256 + tid];
    for (int i = tid; i < NSEL; i += 1024) sk[i] = ~0ULL;   // safety fill
    __syncthreads();
    if (tid == 0) {
        u32 a = 0;
        for (int j = 0; j < 8; ++j) a += ssA[j];
        s_r0 = NSEL - a;      // rank within boundary set
        s_cnt = 0; s_cand = 0;
    }
    if (tid < 64) {
        u32 h0 = hist[tid*4], h1 = hist[tid*4+1], h2 = hist[tid*4+2], h3 = hist[tid*4+3];
        u32 loc = h0 + h1 + h2 + h3;
        u32 p = loc;
        #pragma unroll
        for (int o = 1; o < 64; o <<= 1) { u32 t2 = __shfl_up(p, o); if (lane >= o) p += t2; }
        u32 base = p - loc;
        hsc[tid*4]   = base + h0;
        hsc[tid*4+1] = base + h0 + h1;
        hsc[tid*4+2] = base + h0 + h1 + h2;
        hsc[tid*4+3] = base + h0 + h1 + h2 + h3;
    }
    __syncthreads();
    if (tid < 256) {
        u32 inc = hsc[tid], cb = inc - hist[tid];
        u32 r0 = s_r0;
        if (cb < r0 && r0 <= inc) s_D = tid;
    }
    __syncthreads();
    u32 D48 = s_D;

    // fused parallel load: waves 0-7 -> sure segs (straight to sk);
    // waves 8-15 -> boundary segs filtered by D48 (dg<D48 -> sk, ==D48 -> cand)
    if (wv < 8) {
        int j = wv;
        const u64* SL = gslice + ((size_t)b * 8 + j) * (size_t)PART;
        u32 ns = ssA[j];
        for (u32 i0 = 0; i0 < ns; i0 += 64) {
            u32 i = i0 + lane;
            bool act = i < ns;
            u64 kk = act ? SL[i] : 0ULL;
            u64 bal = __ballot(act);
            u32 base = 0;
            if (lane == 0) base = atomicAdd(&s_cnt, (u32)__popcll(bal));
            base = __shfl(base, 0);
            if (act) sk[base + __popcll(bal & below)] = kk;
        }
    } else {
        int j = wv - 8;
        u32 nc = ccA[j];
        const u64* SL = gslice + ((size_t)b * 8 + j) * (size_t)PART + (PART - nc);
        for (u32 i0 = 0; i0 < nc; i0 += 64) {
            u32 i = i0 + lane;
            bool act = i < nc;
            u64 kk = act ? SL[i] : 0ULL;
            u32 dg = (u32)(kk >> 48) & 0xFFu;
            bool tks = act && (dg < D48);
            bool tkc = act && (dg == D48);
            u64 bs = __ballot(tks), bc = __ballot(tkc);
            u32 base_s = 0, base_c = 0;
            if (lane == 0) {
                if (bs) base_s = atomicAdd(&s_cnt, (u32)__popcll(bs));
                if (bc) base_c = atomicAdd(&s_cand, (u32)__popcll(bc));
            }
            base_s = __shfl(base_s, 0); base_c = __shfl(base_c, 0);
            if (tks) sk[base_s + __popcll(bs & below)] = kk;
            if (tkc) cand[base_c + __popcll(bc & below)] = kk;
        }
    }
    __syncthreads();
    if (tid == 0) s_rank = NSEL - s_cnt;   // re-establish invariant
    __syncthreads();

    // ---- refine within cand (shifts 40,32,8,0); append sure-members each round ----
    const int shifts2[5] = {48, 40, 32, 8, 0};
    for (int rr = 1; ; ++rr) {
        u32 cn = s_cand, r = s_rank;
        if (r == cn || rr == 5) {
            for (u32 i0 = 0; i0 < cn; i0 += 1024) {
                u32 i = i0 + tid;
                bool take = i < cn;
                u64 kk = take ? cand[i] : 0ULL;
                u64 bt = __ballot(take);
                u32 base = 0;
                if (lane == 0 && bt) base = atomicAdd(&s_cnt, (u32)__popcll(bt));
                base = __shfl(base, 0);
                if (take) sk[base + __popcll(bt & below)] = kk;
            }
            break;
        }
        if (r == 1) {
            u64 best = ~0ULL;
            for (u32 i = tid; i < cn; i += 1024) { u64 kk = cand[i]; if (kk < best) best = kk; }
            #pragma unroll
            for (int o = 32; o > 0; o >>= 1) {
                u64 other = __shfl_down(best, o);
                if (other < best) best = other;
            }
            if (lane == 0) s_red[tid >> 6] = best;
            __syncthreads();
            if (tid == 0) {
                u64 m = s_red[0];
                for (int w2 = 1; w2 < 16; ++w2) if (s_red[w2] < m) m = s_red[w2];
                sk[atomicAdd(&s_cnt, 1u)] = m;
            }
            break;
        }
        int shift = shifts2[rr];
        if (tid < 256) hist[tid] = 0;
        __syncthreads();
        for (u32 i = tid; i < cn; i += 1024)
            atomicAdd(&hist[(u32)(cand[i] >> shift) & 0xFFu], 1u);
        __syncthreads();
        if (tid < 64) {
            u32 h0 = hist[tid*4], h1 = hist[tid*4+1], h2 = hist[tid*4+2], h3 = hist[tid*4+3];
            u32 loc = h0 + h1 + h2 + h3;
            u32 p = loc;
            #pragma unroll
            for (int o = 1; o < 64; o <<= 1) { u32 t2 = __shfl_up(p, o); if (lane >= o) p += t2; }
            u32 base = p - loc;
            hsc[tid*4]   = base + h0;
            hsc[tid*4+1] = base + h0 + h1;
            hsc[tid*4+2] = base + h0 + h1 + h2;
            hsc[tid*4+3] = base + h0 + h1 + h2 + h3;
        }
        __syncthreads();
        if (tid < 256) {
            u32 inc = hsc[tid], cb = inc - hist[tid];
            if (cb < r && r <= inc) { s_D = tid; s_rank = r - cb; }
        }
        __syncthreads();
        u32 D = s_D;
        // partition with STATIC-indexed register staging (no scratch)
        u64 vv[11]; bool vb[11];
        #pragma unroll
        for (int it = 0; it < 11; ++it) {
            u32 i = tid + it * 1024;
            vb[it] = (i < cn);
            vv[it] = vb[it] ? cand[i] : 0ULL;
        }
        __syncthreads();
        if (tid == 0) s_cand = 0;
        __syncthreads();
        #pragma unroll
        for (int it = 0; it < 11; ++it) {
            u32 dg = (u32)(vv[it] >> shift) & 0xFFu;
            bool tk = vb[it] && (dg < D);
            u64 bt = __ballot(tk);
            u32 base = 0;
            if (lane == 0 && bt) base = atomicAdd(&s_cnt, (u32)__popcll(bt));
            base = __shfl(base, 0);
            if (tk) sk[base + __popcll(bt & below)] = vv[it];
        }
        #pragma unroll
        for (int it = 0; it < 11; ++it) {
            u32 dg = (u32)(vv[it] >> shift) & 0xFFu;
            bool tk = vb[it] && (dg == D);
            u64 bt = __ballot(tk);
            u32 base = 0;
            if (lane == 0 && bt) base = atomicAdd(&s_cand, (u32)__popcll(bt));
            base = __shfl(base, 0);
            if (tk) cand[base + __popcll(bt & below)] = vv[it];
        }
        __syncthreads();
    }
    __syncthreads();

    // ---- hybrid bitonic sort 2048 keys ascending ----
    {
        int w = tid >> 6, l = lane;
        int base = w * 128;
        u64 a = sk[base + l], c = sk[base + 64 + l];
        #pragma unroll
        for (int k = 2; k <= 128; k <<= 1) {
            for (int j = k >> 1; j > 0; j >>= 1) {
                if (j == 64) {
                    bool dir = (((base + l) & k) == 0);
                    u64 lo = a < c ? a : c;
                    u64 hi = a < c ? c : a;
                    a = dir ? lo : hi;
                    c = dir ? hi : lo;
                } else {
                    bool up_ = (l & j) != 0;
                    bool dira = (((base + l) & k) == 0);
                    bool dirc = (((base + 64 + l) & k) == 0);
                    u64 pa = __shfl_xor(a, j);
                    u64 pc = __shfl_xor(c, j);
                    a = (up_ == dira) ? (a > pa ? a : pa) : (a < pa ? a : pa);
                    c = (up_ == dirc) ? (c > pc ? c : pc) : (c < pc ? c : pc);
                }
            }
        }
        sk[base + l] = a; sk[base + 64 + l] = c;
        __syncthreads();
        for (int k = 256; k <= NSEL; k <<= 1) {
            for (int j = k >> 1; j >= 128; j >>= 1) {
                int n = tid;
                int i = ((n & ~(j - 1)) << 1) | (n & (j - 1));
                int l2 = i | j;
                u64 x = sk[i], y = sk[l2];
                bool up2 = ((i & k) == 0);
                if ((x > y) == up2) { sk[i] = y; sk[l2] = x; }
                __syncthreads();
            }
            a = sk[base + l]; c = sk[base + 64 + l];
            bool dirk = ((base & k) == 0);
            {
                u64 lo = a < c ? a : c;
                u64 hi = a < c ? c : a;
                a = dirk ? lo : hi;
                c = dirk ? hi : lo;
            }
            #pragma unroll
            for (int j = 32; j > 0; j >>= 1) {
                bool up_ = (l & j) != 0;
                u64 pa = __shfl_xor(a, j);
                u64 pc = __shfl_xor(c, j);
                a = (up_ == dirk) ? (a > pa ? a : pa) : (a < pa ? a : pa);
                c = (up_ == dirk) ? (c > pc ? c : pc) : (c < pc ? c : pc);
            }
            sk[base + l] = a; sk[base + 64 + l] = c;
            __syncthreads();
        }
    }

    for (int i = tid; i < NSEL; i += 1024) gskey[(size_t)b * NSEL + i] = sk[i];
    if (tid < NWORD) gkeep[(size_t)b * NWORD + tid] = 0ULL;   // zero for k_cnms
}

// ---- Kernel 4: parallel gather (one rank per thread, 128 blocks) ----
__global__ __launch_bounds__(256) void k_gather(const u64* __restrict__ gskey,
                                                const float4* __restrict__ boxes,
                                                const int* __restrict__ cls,
                                                float4* __restrict__ sel_box,
                                                float4* __restrict__ sel_sbox,
                                                float* __restrict__ sel_area,
                                                float* __restrict__ sel_score,
                                                int* __restrict__ sel_cls) {
    int b = blockIdx.y;
    int r = blockIdx.x * 256 + threadIdx.x;
    u64 key = gskey[(size_t)b * NSEL + r];
    int a = (int)(key & 0xFFFFFFFFu);
    if ((unsigned)a >= NANCH) a = 0;   // fault-safe
    size_t src = (size_t)b * NANCH + a;
    float4 bx = boxes[src];
    int c = cls[src];
    float sc = dec_score(key);
    float off = (float)c * MAXWH;
    float4 sb;
    sb.x = bx.x + off; sb.y = bx.y + off;
    sb.z = bx.z + off; sb.w = bx.w + off;
    float area = (sb.z - sb.x) * (sb.w - sb.y);
    size_t o = (size_t)b * NSEL + r;
    sel_box[o] = bx; sel_sbox[o] = sb; sel_area[o] = area;
    sel_score[o] = sc; sel_cls[o] = c;
}

// ---- Kernel 5: per-class NMS (IoU matrix is block-diagonal by class) ----
__global__ __launch_bounds__(1024) void k_cnms(const float4* __restrict__ sel_sbox,
                                               const float* __restrict__ sel_area,
                                               const int* __restrict__ sel_cls,
                                               const float* __restrict__ sel_score,
                                               u64* __restrict__ gkeep) {
    __shared__ u16 wmem[16][NSEL];    // 64 KB
    __shared__ u64 wkeep[16][NWORD];  // 4 KB

    int b = blockIdx.y;
    int cg = blockIdx.x;
    int lane = threadIdx.x & 63, wv = threadIdx.x >> 6;
    int c = cg * 16 + wv;
    size_t bb = (size_t)b * NSEL;
    const int* CL = sel_cls + bb;
    const float* SC = sel_score + bb;
    u64 below = (1ULL << lane) - 1ULL;

    int n = 0;
    for (int ch = 0; ch < NWORD; ++ch) {
        int i = ch * 64 + lane;
        bool pred = (CL[i] == c) && (SC[i] >= 0.0f);
        u64 bal = __ballot(pred);
        if (pred) wmem[wv][n + __popcll(bal & below)] = (u16)i;
        n += __popcll(bal);
    }

    for (int c0 = 0; c0 < n; c0 += 64) {
        int chunkn = n - c0; if (chunkn > 64) chunkn = 64;
        bool mv = lane < chunkn;
        int q = mv ? (int)wmem[wv][c0 + lane] : 0;
        float4 bq = sel_sbox[bb + q];
        float aq = sel_area[bb + q];

        bool hit = false;
        for (int j = 0; j < c0; ++j) {
            if (!((wkeep[wv][j >> 6] >> (j & 63)) & 1ULL)) continue;
            int p = (int)wmem[wv][j];
            float4 bp = sel_sbox[bb + p];
            float ap = sel_area[bb + p];
            float ltx = fmaxf(bp.x, bq.x), lty = fmaxf(bp.y, bq.y);
            float rbx = fminf(bp.z, bq.z), rby = fminf(bp.w, bq.w);
            float ww = fmaxf(rbx - ltx, 0.0f), hh = fmaxf(rby - lty, 0.0f);
            float inter = ww * hh;
            hit = hit || (mv && (inter / (ap + aq - inter + 1e-16f) > NMS_T));
        }
        u64 avail = __ballot(mv && !hit);

        u64 Rt = 0;
        for (int t = 0; t < chunkn; ++t) {
            int p = (int)wmem[wv][c0 + t];
            float4 bp = sel_sbox[bb + p];
            float ap = sel_area[bb + p];
            float ltx = fmaxf(bp.x, bq.x), lty = fmaxf(bp.y, bq.y);
            float rbx = fminf(bp.z, bq.z), rby = fminf(bp.w, bq.w);
            float ww = fmaxf(rbx - ltx, 0.0f), hh = fmaxf(rby - lty, 0.0f);
            float inter = ww * hh;
            u64 row = __ballot(mv && (inter / (ap + aq - inter + 1e-16f) > NMS_T));
            if (lane == t) Rt = row;
        }

        u64 U = avail, kept = 0;
        while (U) {
            bool inU = ((U >> lane) & 1ULL) != 0ULL;
            u64 newk = __ballot(inU && ((Rt & U & below) == 0ULL));
            u64 killed = __ballot((Rt & newk) != 0ULL);
            kept |= newk;
            U &= ~(newk | killed);
        }
        if (lane == 0) wkeep[wv][c0 >> 6] = kept;
        if ((kept >> lane) & 1ULL)
            atomicOr(&gkeep[(size_t)b * NWORD + (q >> 6)], 1ULL << (q & 63));
    }
}

// ---- Kernel 6: compact kept entries (descending-score order) + zero fill ----
__global__ __launch_bounds__(64) void k_out(const u64* __restrict__ gkeep,
                                            const float4* __restrict__ sel_box,
                                            const float* __restrict__ sel_score,
                                            const int* __restrict__ sel_cls,
                                            float* __restrict__ out) {
    int b = blockIdx.x;
    int lane = threadIdx.x;
    const float* SC = sel_score + (size_t)b * NSEL;
    u64 kreg = (lane < NWORD) ? gkeep[(size_t)b * NWORD + lane] : 0ULL;

    int cnt = (lane < NWORD) ? __popcll(kreg) : 0;
    int pre = cnt;
    #pragma unroll
    for (int dd = 1; dd < 64; dd <<= 1) {
        int o = __shfl_up(pre, dd);
        if (lane >= dd) pre += o;
    }
    int total = __shfl(pre, 63);
    int base = pre - cnt;
    float* OUT = out + (size_t)b * MAXDET * 6;
    if (lane < NWORD) {
        u64 m = kreg;
        int rr = 0;
        while (m) {
            int t = __ffsll((long long)m) - 1;
            m &= m - 1;
            int slot = base + rr; ++rr;
            if (slot < MAXDET) {
                int i = lane * 64 + t;
                size_t src = (size_t)b * NSEL + i;
                float4 bx = sel_box[src];
                float sc = SC[i];
                int c = sel_cls[src];
                float* o6 = OUT + slot * 6;
                o6[0] = bx.x; o6[1] = bx.y; o6[2] = bx.z; o6[3] = bx.w;
                o6[4] = sc; o6[5] = (float)c;
            }
        }
    }
    int start = total > MAXDET ? MAXDET : total;
    for (int s = start + lane; s < MAXDET; s += 64) {
        float* o6 = OUT + s * 6;
        o6[0] = 0.0f; o6[1] = 0.0f; o6[2] = 0.0f;
        o6[3] = 0.0f; o6[4] = 0.0f; o6[5] = 0.0f;
    }
}

// ---------------- Launcher (6 nodes) ----------------
extern "C" void kernel_launch(void* const* d_in, const int* in_sizes, int n_in,
                              void* d_out, int out_size, void* d_ws, size_t ws_size,
                              hipStream_t stream) {
    const float* pred = (const float*)d_in[0];
    float* out = (float*)d_out;

    char* ws = (char*)d_ws;
    size_t off = 0;
    auto alloc = [&](size_t bytes) -> void* {
        void* p = ws + off;
        off += (bytes + 255) & ~(size_t)255;
        return p;
    };

    u64*    keys      = (u64*)   alloc((size_t)NBATCH * NSORT * 8);
    float4* boxes     = (float4*)alloc((size_t)NBATCH * NANCH * 16);
    int*    cls       = (int*)   alloc((size_t)NBATCH * NANCH * 4);
    u32*    bhist     = (u32*)   alloc((size_t)NBATCH * NBLK1 * 256 * 4);
    u32*    ghist2    = (u32*)   alloc((size_t)NBATCH * 256 * 4);
    u64*    gslice    = (u64*)   alloc((size_t)NBATCH * 8 * PART * 8);
    uint2*  gpart     = (uint2*) alloc((size_t)NBATCH * 8 * 8);
    u64*    gskey     = (u64*)   alloc((size_t)NBATCH * NSEL * 8);
    u64*    gkeep     = (u64*)   alloc((size_t)NBATCH * NWORD * 8);
    float4* sel_box   = (float4*)alloc((size_t)NBATCH * NSEL * 16);
    float4* sel_sbox  = (float4*)alloc((size_t)NBATCH * NSEL * 16);
    float*  sel_area  = (float*) alloc((size_t)NBATCH * NSEL * 4);
    float*  sel_score = (float*) alloc((size_t)NBATCH * NSEL * 4);
    int*    sel_cls   = (int*)   alloc((size_t)NBATCH * NSEL * 4);

    dim3 g1(NBLK1, NBATCH);
    k_prep<<<g1, 256, 0, stream>>>(pred, keys, boxes, cls, bhist, ghist2);

    dim3 g2(8, NBATCH);
    k_scan<<<g2, 1024, 0, stream>>>(keys, bhist, gslice, gpart, ghist2);

    k_fin<<<NBATCH, 1024, 0, stream>>>(gslice, gpart, ghist2, gskey, gkeep);

    dim3 g4(8, NBATCH);
    k_gather<<<g4, 256, 0, stream>>>(gskey, boxes, cls,
                                     sel_box, sel_sbox, sel_area,
                                     sel_score, sel_cls);

    dim3 g5(5, NBATCH);
    k_cnms<<<g5, 1024, 0, stream>>>(sel_sbox, sel_area, sel_cls, sel_score, gkeep);

    k_out<<<NBATCH, 64, 0, stream>>>(gkeep, sel_box, sel_score, sel_cls, out);
}